// Round 3
// baseline (2998.184 us; speedup 1.0000x reference)
//
#include <hip/hip_runtime.h>
#include <hip/hip_bf16.h>
#include <cmath>

// Problem: N=64, T=512, D=256, H=256 (all fp32)
//   c   = x @ Wx + b          (N,T,H)  -- parallel GEMM (phase 1, into d_out)
//   h_t = tanh(c_t + h_{t-1} @ Wh)     -- sequential scan (phase 2, in place)
//
// R3 scan: TRUE register-resident Wh. R1/R2 post-mortem: VGPR_Count (60/140)
// proved the compiler sank the Wh loads back into the t-loop (const+restrict
// makes remat legal) -> Wh was re-streamed from L2 every step. R1's 16 waves
// hid it partially (930 ns/step); R2's 4 waves exposed full latency (3.6 us).
// Fix: pin each W value with asm volatile("" : "+v"(w)) -- opaque value,
// remat impossible. 64 floats/thread (K=16 x C=4), 1024 threads (16 waves:
// TLP for barriers/LDS), ~90 VGPR < 128 cap from launch_bounds(1024,4).

#define KDIM  256
#define HDIM  256
#define TSTEPS 512
#define NBATCH 64

__device__ __forceinline__ float fast_tanh(float s) {
    float a = fabsf(s);
    float e = __expf(-2.0f * a);
    float r = (1.0f - e) * __builtin_amdgcn_rcpf(1.0f + e);
    return s < 0.0f ? -r : r;
}

// ---------------- Phase 1: c = x @ Wx + b ----------------
// 128x128 tile, 256 threads, 8x8 outputs/thread, K-chunks of 32. (unchanged)
__global__ __launch_bounds__(256, 2) void xw_gemm(
    const float* __restrict__ x,    // (32768, 256)
    const float* __restrict__ Wx,   // (256, 256)
    const float* __restrict__ bias, // (256)
    float* __restrict__ out)        // (32768, 256)
{
    __shared__ float As[32][132];   // [k][m]
    __shared__ float Bs[32][132];   // [k][n]

    const int tid = threadIdx.x;
    const int mt = tid >> 4;
    const int nt = tid & 15;
    const int m0 = blockIdx.x * 128;
    const int n0 = blockIdx.y * 128;

    float acc[8][8];
#pragma unroll
    for (int i = 0; i < 8; ++i)
#pragma unroll
        for (int j = 0; j < 8; ++j) acc[i][j] = 0.f;

    for (int kc = 0; kc < KDIM; kc += 32) {
        {
            const int k4 = tid & 7;
            const int mr = tid >> 3;
#pragma unroll
            for (int p = 0; p < 4; ++p) {
                int mrow = mr + 32 * p;
                float4 v = *(const float4*)&x[(size_t)(m0 + mrow) * KDIM + kc + 4 * k4];
                As[4 * k4 + 0][mrow] = v.x;
                As[4 * k4 + 1][mrow] = v.y;
                As[4 * k4 + 2][mrow] = v.z;
                As[4 * k4 + 3][mrow] = v.w;
            }
        }
        {
            const int nn = 4 * (tid & 31);
            const int kr = tid >> 5;
#pragma unroll
            for (int p = 0; p < 4; ++p) {
                int krow = kr + 8 * p;
                float4 v = *(const float4*)&Wx[(size_t)(kc + krow) * HDIM + n0 + nn];
                *(float4*)&Bs[krow][nn] = v;
            }
        }
        __syncthreads();

#pragma unroll 4
        for (int k = 0; k < 32; ++k) {
            float4 a0 = *(const float4*)&As[k][8 * mt];
            float4 a1 = *(const float4*)&As[k][8 * mt + 4];
            float4 b0 = *(const float4*)&Bs[k][8 * nt];
            float4 b1 = *(const float4*)&Bs[k][8 * nt + 4];
            float av[8] = {a0.x, a0.y, a0.z, a0.w, a1.x, a1.y, a1.z, a1.w};
            float bv[8] = {b0.x, b0.y, b0.z, b0.w, b1.x, b1.y, b1.z, b1.w};
#pragma unroll
            for (int i = 0; i < 8; ++i)
#pragma unroll
                for (int j = 0; j < 8; ++j) acc[i][j] += av[i] * bv[j];
        }
        __syncthreads();
    }

    float4 bj0 = *(const float4*)&bias[n0 + 8 * nt];
    float4 bj1 = *(const float4*)&bias[n0 + 8 * nt + 4];
    float bb[8] = {bj0.x, bj0.y, bj0.z, bj0.w, bj1.x, bj1.y, bj1.z, bj1.w};
#pragma unroll
    for (int i = 0; i < 8; ++i) {
        float4 v0, v1;
        v0.x = acc[i][0] + bb[0]; v0.y = acc[i][1] + bb[1];
        v0.z = acc[i][2] + bb[2]; v0.w = acc[i][3] + bb[3];
        v1.x = acc[i][4] + bb[4]; v1.y = acc[i][5] + bb[5];
        v1.z = acc[i][6] + bb[6]; v1.w = acc[i][7] + bb[7];
        float* o = &out[(size_t)(m0 + 8 * mt + i) * HDIM + n0 + 8 * nt];
        *(float4*)&o[0] = v0;
        *(float4*)&o[4] = v1;
    }
}

// ---------------- Phase 2: sequential scan ----------------
// 1024 threads. Wave g (=tid>>6) owns k in [16g,16g+16); lane owns columns
// {lane+64c, c<4}. W = 64 VGPRs/thread, asm-pinned. h reads = 4 broadcast
// ds_read_b128 per wave per step. Reduction: 4 ds_add_f32/thread into a
// double-buffered accumulator pre-seeded with c_t.
__global__ __launch_bounds__(1024, 4) void rnn_scan(
    const float* __restrict__ h0,   // (64, 256)
    const float* __restrict__ Wh,   // (256, 256)
    float* __restrict__ out)        // (64, 512, 256): holds c, overwritten by h
{
    const int r    = blockIdx.x;
    const int tid  = threadIdx.x;
    const int lane = tid & 63;
    const int g    = tid >> 6;      // wave index = k-group

    __shared__ float hbuf[256];
    __shared__ float accb[2][256];

    // W[i][c] = Wh[16g+i][lane+64c]  (64 VGPRs, coalesced load along lane)
    float W[16][4];
    {
        const float* wp = Wh + (size_t)(16 * g) * HDIM + lane;
#pragma unroll
        for (int i = 0; i < 16; ++i)
#pragma unroll
            for (int c = 0; c < 4; ++c)
                W[i][c] = wp[(size_t)i * HDIM + 64 * c];
    }
    // Pin: value becomes opaque -> compiler cannot re-load from Wh in-loop.
#pragma unroll
    for (int i = 0; i < 16; ++i)
#pragma unroll
        for (int c = 0; c < 4; ++c)
            asm volatile("" : "+v"(W[i][c]));

    float* outr = out + (size_t)r * TSTEPS * HDIM;

    if (tid < 256) {
        hbuf[tid]    = h0[(size_t)r * HDIM + tid];
        accb[0][tid] = outr[tid];    // pre-seed step-0 accumulator with c_0
    }
    __syncthreads();

    const float4* hv = (const float4*)(hbuf + 16 * g);

#pragma unroll 1
    for (int t = 0; t < TSTEPS; ++t) {
        float* cur = accb[t & 1];
        float* nxt = accb[(t & 1) ^ 1];

        // Prefetch c_{t+1}; latency hidden behind FMA phase.
        int tn = (t + 1 < TSTEPS) ? t + 1 : t;
        float cnext = 0.f;
        if (tid < 256) cnext = outr[(size_t)tn * HDIM + tid];

        // FMA: acc[c] = sum_{i<16} h[16g+i] * Wh[16g+i][lane+64c]
        float acc[4] = {0.f, 0.f, 0.f, 0.f};
#pragma unroll
        for (int q = 0; q < 4; ++q) {
            float4 hh = hv[q];         // broadcast ds_read_b128
#pragma unroll
            for (int c = 0; c < 4; ++c) {
                acc[c] += hh.x * W[4 * q + 0][c];
                acc[c] += hh.y * W[4 * q + 1][c];
                acc[c] += hh.z * W[4 * q + 2][c];
                acc[c] += hh.w * W[4 * q + 3][c];
            }
        }
#pragma unroll
        for (int c = 0; c < 4; ++c)
            atomicAdd(&cur[lane + 64 * c], acc[c]);   // ds_add_f32
        __syncthreads();

        if (tid < 256) {
            float hn = fast_tanh(cur[tid]);
            outr[(size_t)t * HDIM + tid] = hn;   // in-place; c_t consumed
            hbuf[tid] = hn;                      // all FMA reads done (barrier)
            nxt[tid]  = cnext;                   // seed next accumulator
        }
        __syncthreads();
    }
}

extern "C" void kernel_launch(void* const* d_in, const int* in_sizes, int n_in,
                              void* d_out, int out_size, void* d_ws, size_t ws_size,
                              hipStream_t stream) {
    const float* x  = (const float*)d_in[0];   // (64,512,256)
    const float* h0 = (const float*)d_in[1];   // (64,256)
    const float* Wx = (const float*)d_in[2];   // (256,256)
    const float* Wh = (const float*)d_in[3];   // (256,256)
    const float* b  = (const float*)d_in[4];   // (256)
    float* out = (float*)d_out;                // (64,512,256)

    dim3 g1(32768 / 128, HDIM / 128);
    xw_gemm<<<g1, 256, 0, stream>>>(x, Wx, b, out);

    rnn_scan<<<NBATCH, 1024, 0, stream>>>(h0, Wh, out);
}

// Round 4
// 1730.954 us; speedup vs baseline: 1.7321x; 1.7321x over previous
//
#include <hip/hip_runtime.h>
#include <hip/hip_bf16.h>
#include <cmath>

// Problem: N=64, T=512, D=256, H=256 (all fp32)
//   c   = x @ Wx + b          (N,T,H)  -- parallel GEMM (phase 1, into d_out)
//   h_t = tanh(c_t + h_{t-1} @ Wh)     -- sequential scan (phase 2, in place)
//
// R4 scan: register-resident Wh via NAMED SCALARS. R1-R3 post-mortem: the
// compiler never kept an indexed local array live across the t-loop --
// R1/R2 sank the loads (L2 re-stream), R3's per-element asm pins left W in
// an unpromoted stack alloca (VGPR_Count=44 -> scratch, 5.6us/step). Named
// scalar variables cannot fail SROA/mem2reg. 512 threads (8 waves), wave g
// owns k in [32g,32g+32), lane owns cols {lane+64c}: 128 W-scalars/thread,
// cap 256 VGPRs (launch_bounds(512,2)) -> ~90 regs slack, no spill pressure.

#define KDIM  256
#define HDIM  256
#define TSTEPS 512
#define NBATCH 64

__device__ __forceinline__ float fast_tanh(float s) {
    float a = fabsf(s);
    float e = __expf(-2.0f * a);
    float r = (1.0f - e) * __builtin_amdgcn_rcpf(1.0f + e);
    return s < 0.0f ? -r : r;
}

// ---------------- Phase 1: c = x @ Wx + b ----------------
// 128x128 tile, 256 threads, 8x8 outputs/thread, K-chunks of 32. (unchanged)
__global__ __launch_bounds__(256, 2) void xw_gemm(
    const float* __restrict__ x,    // (32768, 256)
    const float* __restrict__ Wx,   // (256, 256)
    const float* __restrict__ bias, // (256)
    float* __restrict__ out)        // (32768, 256)
{
    __shared__ float As[32][132];   // [k][m]
    __shared__ float Bs[32][132];   // [k][n]

    const int tid = threadIdx.x;
    const int mt = tid >> 4;
    const int nt = tid & 15;
    const int m0 = blockIdx.x * 128;
    const int n0 = blockIdx.y * 128;

    float acc[8][8];
#pragma unroll
    for (int i = 0; i < 8; ++i)
#pragma unroll
        for (int j = 0; j < 8; ++j) acc[i][j] = 0.f;

    for (int kc = 0; kc < KDIM; kc += 32) {
        {
            const int k4 = tid & 7;
            const int mr = tid >> 3;
#pragma unroll
            for (int p = 0; p < 4; ++p) {
                int mrow = mr + 32 * p;
                float4 v = *(const float4*)&x[(size_t)(m0 + mrow) * KDIM + kc + 4 * k4];
                As[4 * k4 + 0][mrow] = v.x;
                As[4 * k4 + 1][mrow] = v.y;
                As[4 * k4 + 2][mrow] = v.z;
                As[4 * k4 + 3][mrow] = v.w;
            }
        }
        {
            const int nn = 4 * (tid & 31);
            const int kr = tid >> 5;
#pragma unroll
            for (int p = 0; p < 4; ++p) {
                int krow = kr + 8 * p;
                float4 v = *(const float4*)&Wx[(size_t)(kc + krow) * HDIM + n0 + nn];
                *(float4*)&Bs[krow][nn] = v;
            }
        }
        __syncthreads();

#pragma unroll 4
        for (int k = 0; k < 32; ++k) {
            float4 a0 = *(const float4*)&As[k][8 * mt];
            float4 a1 = *(const float4*)&As[k][8 * mt + 4];
            float4 b0 = *(const float4*)&Bs[k][8 * nt];
            float4 b1 = *(const float4*)&Bs[k][8 * nt + 4];
            float av[8] = {a0.x, a0.y, a0.z, a0.w, a1.x, a1.y, a1.z, a1.w};
            float bv[8] = {b0.x, b0.y, b0.z, b0.w, b1.x, b1.y, b1.z, b1.w};
#pragma unroll
            for (int i = 0; i < 8; ++i)
#pragma unroll
                for (int j = 0; j < 8; ++j) acc[i][j] += av[i] * bv[j];
        }
        __syncthreads();
    }

    float4 bj0 = *(const float4*)&bias[n0 + 8 * nt];
    float4 bj1 = *(const float4*)&bias[n0 + 8 * nt + 4];
    float bb[8] = {bj0.x, bj0.y, bj0.z, bj0.w, bj1.x, bj1.y, bj1.z, bj1.w};
#pragma unroll
    for (int i = 0; i < 8; ++i) {
        float4 v0, v1;
        v0.x = acc[i][0] + bb[0]; v0.y = acc[i][1] + bb[1];
        v0.z = acc[i][2] + bb[2]; v0.w = acc[i][3] + bb[3];
        v1.x = acc[i][4] + bb[4]; v1.y = acc[i][5] + bb[5];
        v1.z = acc[i][6] + bb[6]; v1.w = acc[i][7] + bb[7];
        float* o = &out[(size_t)(m0 + 8 * mt + i) * HDIM + n0 + 8 * nt];
        *(float4*)&o[0] = v0;
        *(float4*)&o[4] = v1;
    }
}

// ---------------- Phase 2: sequential scan ----------------
// 512 threads = 8 waves. Wave g = tid>>6 owns k in [32g,32g+32); lane owns
// columns {lane+64c, c<4}. 128 named W scalars per thread (no array!).
// Reduction: 4 ds_add_f32/thread into double-buffered accumulator pre-seeded
// with c_t. Columns stride 64 -> ds_add addresses lane+64c -> 2 lanes/bank
// (free, m136).

// wA/wB/wC/wD = columns lane+0/64/128/192 for k-row 32g+i.
#define W_DECL(i)  float wA##i, wB##i, wC##i, wD##i;
#define W_LOAD(i)  wA##i = wp[(i) * 256];       wB##i = wp[(i) * 256 + 64]; \
                   wC##i = wp[(i) * 256 + 128]; wD##i = wp[(i) * 256 + 192];
#define W_PIN(i)   asm volatile("" : "+v"(wA##i), "+v"(wB##i), "+v"(wC##i), "+v"(wD##i));
#define W_FMA(hc, i) a0 += (hc) * wA##i; a1 += (hc) * wB##i; \
                     a2 += (hc) * wC##i; a3 += (hc) * wD##i;
#define W_FMAQ(q, i0, i1, i2, i3) { float4 hq = hv[q]; \
    W_FMA(hq.x, i0) W_FMA(hq.y, i1) W_FMA(hq.z, i2) W_FMA(hq.w, i3) }

#define REP32(M) M(0) M(1) M(2) M(3) M(4) M(5) M(6) M(7) \
                 M(8) M(9) M(10) M(11) M(12) M(13) M(14) M(15) \
                 M(16) M(17) M(18) M(19) M(20) M(21) M(22) M(23) \
                 M(24) M(25) M(26) M(27) M(28) M(29) M(30) M(31)

__global__ __launch_bounds__(512, 2) void rnn_scan(
    const float* __restrict__ h0,   // (64, 256)
    const float* __restrict__ Wh,   // (256, 256)
    float* __restrict__ out)        // (64, 512, 256): holds c, overwritten by h
{
    const int r    = blockIdx.x;
    const int tid  = threadIdx.x;
    const int lane = tid & 63;
    const int g    = tid >> 6;      // wave index = k-group, k in [32g,32g+32)

    __shared__ float hbuf[256];
    __shared__ float accb[2][256];

    REP32(W_DECL)
    {
        const float* wp = Wh + (size_t)(32 * g) * HDIM + lane;
        REP32(W_LOAD)
    }
    REP32(W_PIN)

    float* outr = out + (size_t)r * TSTEPS * HDIM;

    if (tid < 256) {
        hbuf[tid]    = h0[(size_t)r * HDIM + tid];
        accb[0][tid] = outr[tid];    // pre-seed step-0 accumulator with c_0
    }
    __syncthreads();

    const float4* hv = (const float4*)(hbuf + 32 * g);

#pragma unroll 1
    for (int t = 0; t < TSTEPS; ++t) {
        float* cur = accb[t & 1];
        float* nxt = accb[(t & 1) ^ 1];

        // Prefetch c_{t+1}; latency hidden behind FMA phase.
        int tn = (t + 1 < TSTEPS) ? t + 1 : t;
        float cnext = 0.f;
        if (tid < 256) cnext = outr[(size_t)tn * HDIM + tid];

        // FMA: acc_c = sum_{i<32} h[32g+i] * Wh[32g+i][lane+64c]
        float a0 = 0.f, a1 = 0.f, a2 = 0.f, a3 = 0.f;
        W_FMAQ(0,  0,  1,  2,  3)
        W_FMAQ(1,  4,  5,  6,  7)
        W_FMAQ(2,  8,  9, 10, 11)
        W_FMAQ(3, 12, 13, 14, 15)
        W_FMAQ(4, 16, 17, 18, 19)
        W_FMAQ(5, 20, 21, 22, 23)
        W_FMAQ(6, 24, 25, 26, 27)
        W_FMAQ(7, 28, 29, 30, 31)

        atomicAdd(&cur[lane],       a0);   // ds_add_f32, conflict-free
        atomicAdd(&cur[lane + 64],  a1);
        atomicAdd(&cur[lane + 128], a2);
        atomicAdd(&cur[lane + 192], a3);
        __syncthreads();

        if (tid < 256) {
            float hn = fast_tanh(cur[tid]);
            outr[(size_t)t * HDIM + tid] = hn;   // in-place; c_t consumed
            hbuf[tid] = hn;                      // FMA reads done (barrier)
            nxt[tid]  = cnext;                   // seed next accumulator
        }
        __syncthreads();
    }
}

extern "C" void kernel_launch(void* const* d_in, const int* in_sizes, int n_in,
                              void* d_out, int out_size, void* d_ws, size_t ws_size,
                              hipStream_t stream) {
    const float* x  = (const float*)d_in[0];   // (64,512,256)
    const float* h0 = (const float*)d_in[1];   // (64,256)
    const float* Wx = (const float*)d_in[2];   // (256,256)
    const float* Wh = (const float*)d_in[3];   // (256,256)
    const float* b  = (const float*)d_in[4];   // (256)
    float* out = (float*)d_out;                // (64,512,256)

    dim3 g1(32768 / 128, HDIM / 128);
    xw_gemm<<<g1, 256, 0, stream>>>(x, Wx, b, out);

    rnn_scan<<<NBATCH, 512, 0, stream>>>(h0, Wh, out);
}

// Round 5
// 1730.142 us; speedup vs baseline: 1.7329x; 1.0005x over previous
//
#include <hip/hip_runtime.h>
#include <hip/hip_bf16.h>
#include <cmath>

// Problem: N=64, T=512, D=256, H=256 (all fp32)
//   c   = x @ Wx + b          (N,T,H)  -- parallel GEMM (phase 1, into d_out)
//   h_t = tanh(c_t + h_{t-1} @ Wh)     -- sequential scan (phase 2, in place)
//
// R5 scan: R4's named-scalar register-resident Wh, with the occupancy
// attribute fixed. R1-R4 post-mortem: __launch_bounds__ arg2 behaves as
// CUDA's min-BLOCKS-per-CU -> waves/EU = arg2*waves_per_block/4:
//   R3 (1024,4) -> 8 waves/EU -> 64-VGPR budget  -> spill (VGPR 44)
//   R4 (512,2)  -> 4 waves/EU -> 128-VGPR budget -> spill (VGPR 80, 1.6ms
//                  scratch reload of ~90 W-values x 512 steps)
// Fix: amdgpu_waves_per_eu(2,2) exactly -> 256-VGPR budget >= ~170 demand,
// and max=2 disables occupancy-driven spill heuristics.

#define KDIM  256
#define HDIM  256
#define TSTEPS 512
#define NBATCH 64

__device__ __forceinline__ float fast_tanh(float s) {
    float a = fabsf(s);
    float e = __expf(-2.0f * a);
    float r = (1.0f - e) * __builtin_amdgcn_rcpf(1.0f + e);
    return s < 0.0f ? -r : r;
}

// ---------------- Phase 1: c = x @ Wx + b ----------------
// 128x128 tile, 256 threads, 8x8 outputs/thread, K-chunks of 32. (unchanged)
__global__ __launch_bounds__(256, 2) void xw_gemm(
    const float* __restrict__ x,    // (32768, 256)
    const float* __restrict__ Wx,   // (256, 256)
    const float* __restrict__ bias, // (256)
    float* __restrict__ out)        // (32768, 256)
{
    __shared__ float As[32][132];   // [k][m]
    __shared__ float Bs[32][132];   // [k][n]

    const int tid = threadIdx.x;
    const int mt = tid >> 4;
    const int nt = tid & 15;
    const int m0 = blockIdx.x * 128;
    const int n0 = blockIdx.y * 128;

    float acc[8][8];
#pragma unroll
    for (int i = 0; i < 8; ++i)
#pragma unroll
        for (int j = 0; j < 8; ++j) acc[i][j] = 0.f;

    for (int kc = 0; kc < KDIM; kc += 32) {
        {
            const int k4 = tid & 7;
            const int mr = tid >> 3;
#pragma unroll
            for (int p = 0; p < 4; ++p) {
                int mrow = mr + 32 * p;
                float4 v = *(const float4*)&x[(size_t)(m0 + mrow) * KDIM + kc + 4 * k4];
                As[4 * k4 + 0][mrow] = v.x;
                As[4 * k4 + 1][mrow] = v.y;
                As[4 * k4 + 2][mrow] = v.z;
                As[4 * k4 + 3][mrow] = v.w;
            }
        }
        {
            const int nn = 4 * (tid & 31);
            const int kr = tid >> 5;
#pragma unroll
            for (int p = 0; p < 4; ++p) {
                int krow = kr + 8 * p;
                float4 v = *(const float4*)&Wx[(size_t)(kc + krow) * HDIM + n0 + nn];
                *(float4*)&Bs[krow][nn] = v;
            }
        }
        __syncthreads();

#pragma unroll 4
        for (int k = 0; k < 32; ++k) {
            float4 a0 = *(const float4*)&As[k][8 * mt];
            float4 a1 = *(const float4*)&As[k][8 * mt + 4];
            float4 b0 = *(const float4*)&Bs[k][8 * nt];
            float4 b1 = *(const float4*)&Bs[k][8 * nt + 4];
            float av[8] = {a0.x, a0.y, a0.z, a0.w, a1.x, a1.y, a1.z, a1.w};
            float bv[8] = {b0.x, b0.y, b0.z, b0.w, b1.x, b1.y, b1.z, b1.w};
#pragma unroll
            for (int i = 0; i < 8; ++i)
#pragma unroll
                for (int j = 0; j < 8; ++j) acc[i][j] += av[i] * bv[j];
        }
        __syncthreads();
    }

    float4 bj0 = *(const float4*)&bias[n0 + 8 * nt];
    float4 bj1 = *(const float4*)&bias[n0 + 8 * nt + 4];
    float bb[8] = {bj0.x, bj0.y, bj0.z, bj0.w, bj1.x, bj1.y, bj1.z, bj1.w};
#pragma unroll
    for (int i = 0; i < 8; ++i) {
        float4 v0, v1;
        v0.x = acc[i][0] + bb[0]; v0.y = acc[i][1] + bb[1];
        v0.z = acc[i][2] + bb[2]; v0.w = acc[i][3] + bb[3];
        v1.x = acc[i][4] + bb[4]; v1.y = acc[i][5] + bb[5];
        v1.z = acc[i][6] + bb[6]; v1.w = acc[i][7] + bb[7];
        float* o = &out[(size_t)(m0 + 8 * mt + i) * HDIM + n0 + 8 * nt];
        *(float4*)&o[0] = v0;
        *(float4*)&o[4] = v1;
    }
}

// ---------------- Phase 2: sequential scan ----------------
// 512 threads = 8 waves, exactly 2 waves/EU (1 block/CU). Wave g = tid>>6
// owns k in [32g,32g+32); lane owns columns {lane+64c, c<4}. 128 named W
// scalars per thread, asm-pinned. Reduction: 4 ds_add_f32/thread into
// double-buffered accumulator pre-seeded with c_t.

#define W_DECL(i)  float wA##i, wB##i, wC##i, wD##i;
#define W_LOAD(i)  wA##i = wp[(i) * 256];       wB##i = wp[(i) * 256 + 64]; \
                   wC##i = wp[(i) * 256 + 128]; wD##i = wp[(i) * 256 + 192];
#define W_PIN(i)   asm volatile("" : "+v"(wA##i), "+v"(wB##i), "+v"(wC##i), "+v"(wD##i));
#define W_FMA(hc, i) a0 += (hc) * wA##i; a1 += (hc) * wB##i; \
                     a2 += (hc) * wC##i; a3 += (hc) * wD##i;
#define W_FMAQ(q, i0, i1, i2, i3) { float4 hq = hv[q]; \
    W_FMA(hq.x, i0) W_FMA(hq.y, i1) W_FMA(hq.z, i2) W_FMA(hq.w, i3) }

#define REP32(M) M(0) M(1) M(2) M(3) M(4) M(5) M(6) M(7) \
                 M(8) M(9) M(10) M(11) M(12) M(13) M(14) M(15) \
                 M(16) M(17) M(18) M(19) M(20) M(21) M(22) M(23) \
                 M(24) M(25) M(26) M(27) M(28) M(29) M(30) M(31)

__global__
__attribute__((amdgpu_flat_work_group_size(512, 512), amdgpu_waves_per_eu(2, 2)))
void rnn_scan(
    const float* __restrict__ h0,   // (64, 256)
    const float* __restrict__ Wh,   // (256, 256)
    float* __restrict__ out)        // (64, 512, 256): holds c, overwritten by h
{
    const int r    = blockIdx.x;
    const int tid  = threadIdx.x;
    const int lane = tid & 63;
    const int g    = tid >> 6;      // wave index = k-group, k in [32g,32g+32)

    __shared__ float hbuf[256];
    __shared__ float accb[2][256];

    REP32(W_DECL)
    {
        const float* wp = Wh + (size_t)(32 * g) * HDIM + lane;
        REP32(W_LOAD)
    }
    REP32(W_PIN)

    float* outr = out + (size_t)r * TSTEPS * HDIM;

    if (tid < 256) {
        hbuf[tid]    = h0[(size_t)r * HDIM + tid];
        accb[0][tid] = outr[tid];    // pre-seed step-0 accumulator with c_0
    }
    __syncthreads();

    const float4* hv = (const float4*)(hbuf + 32 * g);

#pragma unroll 1
    for (int t = 0; t < TSTEPS; ++t) {
        float* cur = accb[t & 1];
        float* nxt = accb[(t & 1) ^ 1];

        // Prefetch c_{t+1}; latency hidden behind FMA phase.
        int tn = (t + 1 < TSTEPS) ? t + 1 : t;
        float cnext = 0.f;
        if (tid < 256) cnext = outr[(size_t)tn * HDIM + tid];

        // FMA: acc_c = sum_{i<32} h[32g+i] * Wh[32g+i][lane+64c]
        float a0 = 0.f, a1 = 0.f, a2 = 0.f, a3 = 0.f;
        W_FMAQ(0,  0,  1,  2,  3)
        W_FMAQ(1,  4,  5,  6,  7)
        W_FMAQ(2,  8,  9, 10, 11)
        W_FMAQ(3, 12, 13, 14, 15)
        W_FMAQ(4, 16, 17, 18, 19)
        W_FMAQ(5, 20, 21, 22, 23)
        W_FMAQ(6, 24, 25, 26, 27)
        W_FMAQ(7, 28, 29, 30, 31)

        atomicAdd(&cur[lane],       a0);   // ds_add_f32, 2 lanes/bank: free
        atomicAdd(&cur[lane + 64],  a1);
        atomicAdd(&cur[lane + 128], a2);
        atomicAdd(&cur[lane + 192], a3);
        __syncthreads();

        if (tid < 256) {
            float hn = fast_tanh(cur[tid]);
            outr[(size_t)t * HDIM + tid] = hn;   // in-place; c_t consumed
            hbuf[tid] = hn;                      // FMA reads done (barrier)
            nxt[tid]  = cnext;                   // seed next accumulator
        }
        __syncthreads();
    }
}

extern "C" void kernel_launch(void* const* d_in, const int* in_sizes, int n_in,
                              void* d_out, int out_size, void* d_ws, size_t ws_size,
                              hipStream_t stream) {
    const float* x  = (const float*)d_in[0];   // (64,512,256)
    const float* h0 = (const float*)d_in[1];   // (64,256)
    const float* Wx = (const float*)d_in[2];   // (256,256)
    const float* Wh = (const float*)d_in[3];   // (256,256)
    const float* b  = (const float*)d_in[4];   // (256)
    float* out = (float*)d_out;                // (64,512,256)

    dim3 g1(32768 / 128, HDIM / 128);
    xw_gemm<<<g1, 256, 0, stream>>>(x, Wx, b, out);

    rnn_scan<<<NBATCH, 512, 0, stream>>>(h0, Wh, out);
}